// Round 6
// baseline (437.161 us; speedup 1.0000x reference)
//
#include <hip/hip_runtime.h>

#define H 2048
#define HH (H * H)
#define NIDX 2097152
#define BINS 256
#define CH 3

// ---------------- ws layout ----------------
// 0     : uint hist_dst[3][256]   (3072)
// 3072  : uint hist_ref[3][256]   (3072)
// 6144  : int  table[3][256]      (3072)
// 9216  : double acc              (8)
// 9232  : uint done_gather
// 9236  : uint done_loss
// 16384 : uint curs[1024]         (4096)
// 20480 : ushort list_g[1024*CAPG] (10.5 MB)
#define NBUCK 512         // pixel buckets (p>>13): 8K pixels = 32KB binpack slice
#define NLIST 1024        // 2 sides x 512
#define CAPG  5120        // per-list cap: mean 4096, sigma 64 -> 16 sigma margin
#define WS_HIST_DST 0
#define WS_HIST_REF 3072
#define WS_TABLE    6144
#define WS_ACC      9216
#define WS_DONE_G   9232
#define WS_DONE_L   9236
#define WS_CURS     16384
#define WS_LIST     20480
#define WS_CTRL_BYTES 20480   // zeroed each call (ctrl + curs)

__device__ __forceinline__ int bin_of(float v) {
    int b = (int)floorf(v);
    return min(max(b, 0), BINS - 1);
}

// ============================================================
// Partition: bucket sample positions by p>>13 into 1024 ushort lists
// (local 13-bit offsets), LDS-staged; global-cursor slow path for tails.
// ============================================================
#define P_BLOCKS 512
#define P_Q4 (NIDX / P_BLOCKS / 4)   // 1024 int4 loads per array per block
#define P_CAP 24                     // LDS stage capacity (Poisson mean 8)

__global__ __launch_bounds__(256) void partition_kernel(
    const int4* __restrict__ idx0, const int4* __restrict__ idx1,
    const int4* __restrict__ idx2, const int4* __restrict__ idx3,
    unsigned short* __restrict__ list_g, unsigned int* __restrict__ curs)
{
    __shared__ unsigned short stage[NLIST * P_CAP];   // 48 KB
    __shared__ unsigned int lcnt[NLIST];              // 4 KB
    for (int i = threadIdx.x; i < NLIST; i += 256) lcnt[i] = 0u;
    __syncthreads();

    const int qbase = blockIdx.x * P_Q4;
    for (int r = 0; r < P_Q4 / 256; ++r) {
        int q = qbase + r * 256 + threadIdx.x;
        int4 a = idx0[q], b = idx1[q], c = idx2[q], d = idx3[q];
        const int pd[4] = { a.x * H + b.x, a.y * H + b.y, a.z * H + b.z, a.w * H + b.w };
        const int pr[4] = { c.x * H + d.x, c.y * H + d.y, c.z * H + d.z, c.w * H + d.w };
        #pragma unroll
        for (int e = 0; e < 4; ++e) {
            {
                int l = pd[e] >> 13;
                unsigned short v = (unsigned short)(pd[e] & 8191);
                unsigned int pos = atomicAdd(&lcnt[l], 1u);
                if (pos < P_CAP) stage[l * P_CAP + pos] = v;
                else {  // rare slow path
                    unsigned int g = atomicAdd(&curs[l], 1u);
                    if (g < CAPG) list_g[(size_t)l * CAPG + g] = v;
                }
            }
            {
                int l = NBUCK + (pr[e] >> 13);
                unsigned short v = (unsigned short)(pr[e] & 8191);
                unsigned int pos = atomicAdd(&lcnt[l], 1u);
                if (pos < P_CAP) stage[l * P_CAP + pos] = v;
                else {
                    unsigned int g = atomicAdd(&curs[l], 1u);
                    if (g < CAPG) list_g[(size_t)l * CAPG + g] = v;
                }
            }
        }
    }
    __syncthreads();
    // flush: each thread owns 4 lists end-to-end
    for (int l = threadIdx.x; l < NLIST; l += 256) {
        unsigned int n = min(lcnt[l], (unsigned int)P_CAP);
        unsigned int base = atomicAdd(&curs[l], n);
        for (unsigned int e = 0; e < n; ++e) {
            unsigned int g = base + e;
            if (g < CAPG) list_g[(size_t)l * CAPG + g] = stage[l * P_CAP + e];
        }
    }
}

// ============================================================
// Gather: one block per (side, bucket). Builds packed bins for its 8K-pixel
// slice in LDS from the coalesced image+mask reads, then consumes its list
// with LDS-only random accesses. Dst side also owns its selected[] slice
// (bitmap in LDS -> coalesced byte writes, no atomics). Last block to finish
// builds the translation table.
// ============================================================
__global__ __launch_bounds__(256) void gather_kernel(
    const unsigned short* __restrict__ list_g, const unsigned int* __restrict__ curs,
    const float* __restrict__ mask_src, const float* __restrict__ mask_tar,
    const float* __restrict__ refimg, const float* __restrict__ tgtimg,
    unsigned char* __restrict__ selected,
    unsigned int* __restrict__ hist_dst, unsigned int* __restrict__ hist_ref,
    int* __restrict__ table, unsigned int* __restrict__ done)
{
    __shared__ unsigned int ldsw[8192];   // packed bins for the slice (32 KB)
    __shared__ unsigned int hist[CH * BINS];
    __shared__ unsigned int bitmap[256];  // 8192 bits
    __shared__ unsigned int is_last;

    const int tid = threadIdx.x;
    const int side = blockIdx.x >> 9;        // 0 = dst(src-mask/ref), 1 = ref(tar-mask/tgt)
    const int bucket = blockIdx.x & (NBUCK - 1);
    const int pbase = bucket << 13;
    const float* mask = side ? mask_tar : mask_src;
    const float* img  = side ? tgtimg  : refimg;

    for (int i = tid; i < CH * BINS; i += 256) hist[i] = 0u;
    bitmap[tid] = 0u;

    // build packed bin words for this slice (coalesced float4 reads)
    for (int q = tid; q < 2048; q += 256) {
        float4 m4 = ((const float4*)(mask + pbase))[q];
        const float mm[4] = { m4.x, m4.y, m4.z, m4.w };
        unsigned int w[4] = { 0u, 0u, 0u, 0u };
        #pragma unroll
        for (int c = 0; c < CH; ++c) {
            float4 v4 = ((const float4*)(img + (size_t)c * HH + pbase))[q];
            const float vv[4] = { v4.x, v4.y, v4.z, v4.w };
            #pragma unroll
            for (int e = 0; e < 4; ++e) {
                float v = (vv[e] * 0.5f + 0.5f) * 255.0f * mm[e];
                w[e] |= ((unsigned int)bin_of(v)) << (8 * c);
            }
        }
        uint4 ow = { w[0], w[1], w[2], w[3] };
        ((uint4*)ldsw)[q] = ow;
    }
    __syncthreads();

    // consume this bucket's list: LDS-only random access
    const int l = side * NBUCK + bucket;
    const unsigned int n = min(curs[l], (unsigned int)CAPG);
    unsigned int zc = 0;   // mask==0 samples (w==0): all 3 channels bin 0
    for (unsigned int i = tid; i < n; i += 256) {
        unsigned int loc = (unsigned int)list_g[(size_t)l * CAPG + i];
        unsigned int w = ldsw[loc];
        if (side == 0) atomicOr(&bitmap[loc >> 5], 1u << (loc & 31));
        if (w == 0u) ++zc;
        else {
            atomicAdd(&hist[0 * BINS + (w & 0xFFu)], 1u);
            atomicAdd(&hist[1 * BINS + ((w >> 8) & 0xFFu)], 1u);
            atomicAdd(&hist[2 * BINS + ((w >> 16) & 0xFFu)], 1u);
        }
    }
    int z = (int)zc;
    #pragma unroll
    for (int off = 32; off; off >>= 1) z += __shfl_down(z, off);
    if ((tid & 63) == 0 && z) {
        atomicAdd(&hist[0 * BINS], (unsigned int)z);
        atomicAdd(&hist[1 * BINS], (unsigned int)z);
        atomicAdd(&hist[2 * BINS], (unsigned int)z);
    }
    __syncthreads();

    // dst blocks own their selected slice: bitmap -> coalesced uint writes
    if (side == 0) {
        unsigned int* sel4 = (unsigned int*)(selected + pbase);
        #pragma unroll
        for (int j = 0; j < 8; ++j) {
            unsigned int u = tid + 256 * j;           // uint index in slice
            unsigned int wv = bitmap[u >> 3];
            unsigned int nib = (wv >> ((u & 7) * 4)) & 0xFu;
            sel4[u] = (nib & 1u) | (((nib >> 1) & 1u) << 8)
                    | (((nib >> 2) & 1u) << 16) | (((nib >> 3) & 1u) << 24);
        }
    }

    // flush histogram
    unsigned int* ghist = side ? hist_ref : hist_dst;
    for (int i = tid; i < CH * BINS; i += 256) {
        unsigned int v = hist[i];
        if (v) atomicAdd(&ghist[i], v);
    }

    // last block builds the table
    __threadfence();
    if (tid == 0) is_last = (atomicAdd(done, 1u) == 2u * NBUCK - 1u) ? 1u : 0u;
    __syncthreads();
    if (is_last) {
        // alias scratch onto ldsw (slice data dead now)
        float* cd = (float*)ldsw;           // 768
        float* cr = (float*)(ldsw + 768);   // 768
        float* wpart = (float*)(ldsw + 1536);
        const int i = tid, lane = i & 63, wave = i >> 6;
        for (int a = 0; a < 6; ++a) {
            unsigned int* h = (a < 3) ? (hist_dst + a * BINS) : (hist_ref + (a - 3) * BINS);
            // coherent read of device-scope-accumulated hist
            float x = (float)atomicAdd(&h[i], 0u);
            #pragma unroll
            for (int off = 1; off < 64; off <<= 1) {
                float y = __shfl_up(x, off);
                if (lane >= off) x += y;
            }
            if (lane == 63) wpart[wave] = x;
            __syncthreads();
            float prefix = 0.0f;
            #pragma unroll
            for (int w = 0; w < 3; ++w) if (w < wave) prefix += wpart[w];
            x += prefix;
            float tot = wpart[0] + wpart[1] + wpart[2] + wpart[3];
            float* out = (a < 3) ? (cd + a * BINS) : (cr + (a - 3) * BINS);
            __syncthreads();
            out[i] = x / tot;
            __syncthreads();
        }
        // exact equivalent of the reference interval search (cr non-decreasing):
        // pos = first index in [1,255] with cr[pos] >= r; found iff cr[pos-1] <= r
        #pragma unroll
        for (int c = 0; c < CH; ++c) {
            int t;
            if (i == 0) t = 0;
            else if (i == BINS - 1) t = BINS - 1;
            else {
                float r = cd[c * BINS + i];
                int lo = 1, hi = BINS - 1;
                while (lo < hi) {
                    int mid = (lo + hi) >> 1;
                    if (cr[c * BINS + mid] < r) lo = mid + 1; else hi = mid;
                }
                t = (cr[c * BINS + lo - 1] <= r) ? lo : i;
            }
            table[c * BINS + i] = t;
        }
    }
}

// ============================================================
// Loss: full-image coalesced pass + fused finalize in last block.
// ============================================================
#define LOSS_BLOCKS 2048

__global__ __launch_bounds__(256) void loss_kernel(
    const float* __restrict__ input, const float* __restrict__ refimg,
    const float* __restrict__ mask_src, const unsigned char* __restrict__ selected,
    const int* __restrict__ table, double* __restrict__ acc,
    unsigned int* __restrict__ done, float* __restrict__ out)
{
    __shared__ int tab[CH * BINS];
    for (int i = threadIdx.x; i < CH * BINS; i += 256) tab[i] = table[i];
    __syncthreads();

    float lsum = 0.0f;
    const int nq = HH / 4;
    const int stride = gridDim.x * 256;
    for (int q = blockIdx.x * 256 + threadIdx.x; q < nq; q += stride) {
        float4 m4 = ((const float4*)mask_src)[q];
        uchar4 s4 = ((const uchar4*)selected)[q];
        const unsigned char ss[4] = { s4.x, s4.y, s4.z, s4.w };
        const float mm[4] = { m4.x, m4.y, m4.z, m4.w };
        #pragma unroll
        for (int c = 0; c < CH; ++c) {
            float4 a4 = ((const float4*)(input + (size_t)c * HH))[q];
            float4 r4 = ((const float4*)(refimg + (size_t)c * HH))[q];
            const float aa[4] = { a4.x, a4.y, a4.z, a4.w };
            const float rr[4] = { r4.x, r4.y, r4.z, r4.w };
            #pragma unroll
            for (int e = 0; e < 4; ++e) {
                float m = mm[e];
                float av = (aa[e] * 0.5f + 0.5f) * 255.0f * m;
                float rv = (rr[e] * 0.5f + 0.5f) * 255.0f * m;
                float tv = (float)tab[c * BINS + bin_of(rv)];
                float mv = m * (ss[e] ? tv : rv);
                lsum += fabsf(av - mv);
            }
        }
    }

    double d = (double)lsum;
    #pragma unroll
    for (int off = 32; off; off >>= 1) d += __shfl_down(d, off);
    __shared__ double wsum[4];
    int wid = threadIdx.x >> 6;
    int lane = threadIdx.x & 63;
    if (lane == 0) wsum[wid] = d;
    __syncthreads();
    if (threadIdx.x == 0) {
        double t = wsum[0] + wsum[1] + wsum[2] + wsum[3];
        atomicAdd(acc, t);
        __threadfence();
        unsigned int old = atomicAdd(done, 1u);
        if (old == (unsigned int)gridDim.x - 1u) {
            double tot = atomicAdd(acc, 0.0);  // coherent read
            out[0] = (float)(tot / (double)(CH * (double)HH));
        }
    }
}

// ============================================================

extern "C" void kernel_launch(void* const* d_in, const int* in_sizes, int n_in,
                              void* d_out, int out_size, void* d_ws, size_t ws_size,
                              hipStream_t stream)
{
    const float* input    = (const float*)d_in[0];
    const float* target   = (const float*)d_in[1];
    const float* mask_src = (const float*)d_in[2];
    const float* mask_tar = (const float*)d_in[3];
    const int*   idx0     = (const int*)d_in[4];
    const int*   idx1     = (const int*)d_in[5];
    const int*   idx2     = (const int*)d_in[6];
    const int*   idx3     = (const int*)d_in[7];
    const float* refimg   = (const float*)d_in[8];

    char* ws = (char*)d_ws;
    unsigned int*   hist_dst = (unsigned int*)(ws + WS_HIST_DST);
    unsigned int*   hist_ref = (unsigned int*)(ws + WS_HIST_REF);
    int*            table    = (int*)(ws + WS_TABLE);
    double*         acc      = (double*)(ws + WS_ACC);
    unsigned int*   done_g   = (unsigned int*)(ws + WS_DONE_G);
    unsigned int*   done_l   = (unsigned int*)(ws + WS_DONE_L);
    unsigned int*   curs     = (unsigned int*)(ws + WS_CURS);
    unsigned short* list_g   = (unsigned short*)(ws + WS_LIST);
    // selected lives after the lists; every byte is written by gather's dst blocks
    unsigned char*  selected = (unsigned char*)(ws + WS_LIST + (size_t)NLIST * CAPG * 2);

    hipMemsetAsync(d_ws, 0, WS_CTRL_BYTES, stream);

    partition_kernel<<<P_BLOCKS, 256, 0, stream>>>((const int4*)idx0, (const int4*)idx1,
                                                   (const int4*)idx2, (const int4*)idx3,
                                                   list_g, curs);
    gather_kernel<<<2 * NBUCK, 256, 0, stream>>>(list_g, curs,
                                                 mask_src, mask_tar, refimg, target,
                                                 selected, hist_dst, hist_ref,
                                                 table, done_g);
    loss_kernel<<<LOSS_BLOCKS, 256, 0, stream>>>(input, refimg, mask_src, selected,
                                                 table, acc, done_l, (float*)d_out);
}